// Round 4
// baseline (612.882 us; speedup 1.0000x reference)
//
#include <hip/hip_runtime.h>
#include <hip/hip_bf16.h>

#define SS 256
#define BB 512
#define II 64
#define HH 128
#define DD 32

typedef __attribute__((ext_vector_type(8))) short short8;   // 8 bf16 (4 VGPRs)
typedef __attribute__((ext_vector_type(4))) float f32x4;

__device__ __forceinline__ short f2bf(float f) {
    unsigned u = __builtin_bit_cast(unsigned, f);
    u += 0x7FFFu + ((u >> 16) & 1u);            // RNE
    return (short)(u >> 16);
}
__device__ __forceinline__ int pack2bf(float a, float b) {
    return (int)((((unsigned)(unsigned short)f2bf(b)) << 16) |
                  ((unsigned)(unsigned short)f2bf(a)));
}
__device__ __forceinline__ short8 load8bf(const float* p) {
    short8 r;
#pragma unroll
    for (int j = 0; j < 8; ++j) r[j] = f2bf(p[j]);
    return r;
}

// barrier with LDS-only drain: ys/out stores and x prefetches stay in flight
__device__ __forceinline__ void sync_lds() {
    __builtin_amdgcn_s_waitcnt(0xc07f);   // lgkmcnt(0); vmcnt/expcnt = max
    __builtin_amdgcn_s_barrier();
}

// ---------------------------------------------------------------------------
// K1: masked per-channel sum / sumsq (f64 accumulators in workspace)
// ---------------------------------------------------------------------------
__global__ __launch_bounds__(256) void stats_kernel(
    const float* __restrict__ v, const int* __restrict__ lengths,
    double* __restrict__ acc_sum, double* __restrict__ acc_sq,
    int C, int rows, int rows_per_block)
{
    __shared__ float red_s[256];
    __shared__ float red_q[256];
    const int tid = threadIdx.x;
    const int c   = tid & (C - 1);
    const int rg  = tid / C;
    const int rpg = 256 / C;
    const int r0  = blockIdx.x * rows_per_block;
    const int r1  = min(rows, r0 + rows_per_block);
    float s = 0.f, q = 0.f;
    for (int r = r0 + rg; r < r1; r += rpg) {
        const int b  = r & (BB - 1);
        const int si = r >> 9;
        if (si < lengths[b]) {
            const float xv = v[r * C + c];
            s += xv;
            q  = fmaf(xv, xv, q);
        }
    }
    red_s[tid] = s; red_q[tid] = q;
    __syncthreads();
    if (rg == 0) {
        for (int g = 1; g < rpg; ++g) { s += red_s[c + g * C]; q += red_q[c + g * C]; }
        atomicAdd(&acc_sum[c], (double)s);
        atomicAdd(&acc_sq[c],  (double)q);
    }
}

// ---------------------------------------------------------------------------
// K2: finalize -> folded BN coefficients  xn = x*a + c
// der layout: [0:64]=a_x [64:128]=c_x [128:160]=a_d [160:192]=c_d
// ---------------------------------------------------------------------------
__global__ __launch_bounds__(128) void finalize_kernel(
    const int* __restrict__ lengths, const double* __restrict__ acc,
    const float* __restrict__ bn_g, const float* __restrict__ bn_b,
    const float* __restrict__ bnd_g, const float* __restrict__ bnd_b,
    float* __restrict__ der)
{
    __shared__ int redc[128];
    __shared__ double s_inv;
    const int tid = threadIdx.x;
    int cs = 0;
    for (int i = tid; i < BB; i += 128) cs += lengths[i];
    redc[tid] = cs;
    __syncthreads();
    if (tid == 0) {
        int tot = 0;
        for (int i = 0; i < 128; ++i) tot += redc[i];
        s_inv = 1.0 / (double)tot;
    }
    __syncthreads();
    const double inv = s_inv;
    if (tid < 64) {
        const double mu  = acc[tid] * inv;
        const double var = acc[64 + tid] * inv - mu * mu;
        const float  rs  = rsqrtf((float)(var + 1e-5));
        const float  a   = rs * bn_g[tid];
        der[tid]      = a;
        der[64 + tid] = bn_b[tid] - (float)mu * a;
    } else if (tid < 96) {
        const int i = tid - 64;
        const double mu  = acc[128 + i] * inv;
        const double var = acc[160 + i] * inv - mu * mu;
        const float  rs  = rsqrtf((float)(var + 1e-5));
        const float  a   = rs * bnd_g[i];
        der[128 + i] = a;
        der[160 + i] = bnd_b[i] - (float)mu * a;
    }
}

// ---------------------------------------------------------------------------
// K3: fused GRU + 3-layer MLP. 32 blocks x 512 threads; block = 16 batch rows.
// Transposed MFMA form: D = W_frag (A) x act_frag (B) -> lane holds 4
// consecutive units x 1 token. Weights VGPR-resident (31 frag-sets).
// MLP pipelined 3 steps behind the recurrence; all LDS double-buffered;
// ONE lgkm-only barrier per step (stores/prefetches stay in flight).
// ---------------------------------------------------------------------------
__global__ __launch_bounds__(512) void gru_mlp_kernel(
    const float* __restrict__ x, const float* __restrict__ xd,
    const int* __restrict__ lengths,
    const float* __restrict__ Wih, const float* __restrict__ Whh,
    const float* __restrict__ bih, const float* __restrict__ bhh,
    const float* __restrict__ W1, const float* __restrict__ b1v,
    const float* __restrict__ W2, const float* __restrict__ b2v,
    const float* __restrict__ W3, const float* __restrict__ b3v,
    const float* __restrict__ der,
    float* __restrict__ out, float* __restrict__ hlast)
{
    __shared__ __align__(16) short hbf[2][16 * 136];
    __shared__ __align__(16) short xbf[2][16 * 72];
    __shared__ __align__(16) short xdbf[2][16 * 40];
    __shared__ __align__(16) short d1b[2][16 * 136];
    __shared__ __align__(16) short d2b[2][16 * 136];

    const int tid  = threadIdx.x;
    const int w    = tid >> 6;
    const int l    = tid & 63;
    const int col  = l & 15;       // B-frag n index = token row
    const int quad = l >> 4;
    const int b0   = blockIdx.x * 16;
    const int ur   = 16 * w + col;        // weight row for A-frags
    const int g0   = 16 * w + quad * 4;   // first output unit of this lane

    // ---- weight A-fragments (persistent in VGPRs) ----
    short8 WR[6], WZ[6], WNh[4], WNx[2], F1[5], F2[4], F3[4];
#pragma unroll
    for (int ks = 0; ks < 4; ++ks) {
        const int ko = ks * 32 + quad * 8;
        WR[ks]  = load8bf(&Whh[(size_t)ur * HH + ko]);
        WZ[ks]  = load8bf(&Whh[(size_t)(HH + ur) * HH + ko]);
        WNh[ks] = load8bf(&Whh[(size_t)(2 * HH + ur) * HH + ko]);
        F2[ks]  = load8bf(&W2[(size_t)ur * HH + ko]);
        F3[ks]  = load8bf(&W3[(size_t)ur * HH + ko]);
    }
#pragma unroll
    for (int ks = 0; ks < 2; ++ks) {
        const int ko = ks * 32 + quad * 8;
        WR[4 + ks] = load8bf(&Wih[(size_t)ur * II + ko]);
        WZ[4 + ks] = load8bf(&Wih[(size_t)(HH + ur) * II + ko]);
        WNx[ks]    = load8bf(&Wih[(size_t)(2 * HH + ur) * II + ko]);
    }
#pragma unroll
    for (int ks = 0; ks < 5; ++ks)
        F1[ks] = load8bf(&W1[(size_t)ur * 160 + ks * 32 + quad * 8]);

    float br_[4], bz_[4], bnh_[4], bnx_[4], bb1_[4], bb2_[4], bb3_[4];
#pragma unroll
    for (int r = 0; r < 4; ++r) {
        const int g = g0 + r;
        br_[r]  = bih[g] + bhh[g];
        bz_[r]  = bih[HH + g] + bhh[HH + g];
        bnh_[r] = bhh[2 * HH + g];
        bnx_[r] = bih[2 * HH + g];
        bb1_[r] = b1v[g]; bb2_[r] = b2v[g]; bb3_[r] = b3v[g];
    }
    const int len = lengths[b0 + col];

    // staging maps
    const int srow = tid >> 5, scol = (tid & 31) * 2;
    const float ax0 = der[scol],      ax1 = der[scol + 1];
    const float cx0 = der[64 + scol], cx1 = der[64 + scol + 1];
    const int drow = tid >> 4, dcol = (tid & 15) * 2;   // tid<256 only
    float ad0 = 0.f, ad1 = 0.f, cd0 = 0.f, cd1 = 0.f;
    if (tid < 256) {
        ad0 = der[128 + dcol]; ad1 = der[128 + dcol + 1];
        cd0 = der[160 + dcol]; cd1 = der[160 + dcol + 1];
    }

    // init: zero h, stage xn[0]
    for (int i = tid; i < 16 * 136 / 2; i += 512) ((int*)hbf[0])[i] = 0;
    float hreg[4] = {0.f, 0.f, 0.f, 0.f};
    {
        const float2 xv = *(const float2*)&x[(size_t)(b0 + srow) * II + scol];
        *(int*)&xbf[0][srow * 72 + scol] =
            pack2bf(fmaf(xv.x, ax0, cx0), fmaf(xv.y, ax1, cx1));
    }
    sync_lds();

    int p = 0;
    for (int t = 0; t < SS + 3; ++t) {
        // global prefetches (drain-free across the barrier)
        float2 xv, dv;
        if (t + 1 < SS)
            xv = *(const float2*)&x[(size_t)((t + 1) * BB + b0 + srow) * II + scol];
        if (t < SS && tid < 256)
            dv = *(const float2*)&xd[(size_t)(t * BB + b0 + drow) * DD + dcol];

        // ---- phase A: L3 for token t-3 ----
        f32x4 a3 = {bb3_[0], bb3_[1], bb3_[2], bb3_[3]};
#pragma unroll
        for (int ks = 0; ks < 4; ++ks)
            a3 = __builtin_amdgcn_mfma_f32_16x16x32_bf16(
                F3[ks], *(const short8*)&d2b[p][col * 136 + ks * 32 + quad * 8], a3, 0, 0, 0);
        if (t >= 3) {
            const int tau = t - 3;
            const bool v = tau < len;
            float4 o;
            o.x = v ? fmaxf(a3[0], 0.f) : 0.f;
            o.y = v ? fmaxf(a3[1], 0.f) : 0.f;
            o.z = v ? fmaxf(a3[2], 0.f) : 0.f;
            o.w = v ? fmaxf(a3[3], 0.f) : 0.f;
            *(float4*)&out[((size_t)tau * BB + b0 + col) * HH + g0] = o;
        }

        // ---- phase B: L2 for token t-2 ----
        f32x4 a2 = {bb2_[0], bb2_[1], bb2_[2], bb2_[3]};
#pragma unroll
        for (int ks = 0; ks < 4; ++ks)
            a2 = __builtin_amdgcn_mfma_f32_16x16x32_bf16(
                F2[ks], *(const short8*)&d1b[p][col * 136 + ks * 32 + quad * 8], a2, 0, 0, 0);
        {
            int2 pk;
            pk.x = pack2bf(fmaxf(a2[0], 0.f), fmaxf(a2[1], 0.f));
            pk.y = pack2bf(fmaxf(a2[2], 0.f), fmaxf(a2[3], 0.f));
            *(int2*)&d2b[p ^ 1][col * 136 + g0] = pk;
        }

        // ---- phase C: gates (step t) + L1 (token t-1), shared h A-frags ----
        short8 Hf[4];
#pragma unroll
        for (int ks = 0; ks < 4; ++ks)
            Hf[ks] = *(const short8*)&hbf[p][col * 136 + ks * 32 + quad * 8];
        const short8 XN0 = *(const short8*)&xbf[p][col * 72 + quad * 8];
        const short8 XN1 = *(const short8*)&xbf[p][col * 72 + 32 + quad * 8];
        const short8 XDf = *(const short8*)&xdbf[p][col * 40 + quad * 8];

        f32x4 ar  = {br_[0],  br_[1],  br_[2],  br_[3]};
        f32x4 az  = {bz_[0],  bz_[1],  bz_[2],  bz_[3]};
        f32x4 anh = {bnh_[0], bnh_[1], bnh_[2], bnh_[3]};
        f32x4 anx = {bnx_[0], bnx_[1], bnx_[2], bnx_[3]};
        f32x4 a1  = {bb1_[0], bb1_[1], bb1_[2], bb1_[3]};
#pragma unroll
        for (int ks = 0; ks < 4; ++ks) {
            ar  = __builtin_amdgcn_mfma_f32_16x16x32_bf16(WR[ks],  Hf[ks], ar,  0, 0, 0);
            az  = __builtin_amdgcn_mfma_f32_16x16x32_bf16(WZ[ks],  Hf[ks], az,  0, 0, 0);
            anh = __builtin_amdgcn_mfma_f32_16x16x32_bf16(WNh[ks], Hf[ks], anh, 0, 0, 0);
            a1  = __builtin_amdgcn_mfma_f32_16x16x32_bf16(F1[ks],  Hf[ks], a1,  0, 0, 0);
        }
        ar  = __builtin_amdgcn_mfma_f32_16x16x32_bf16(WR[4],  XN0, ar,  0, 0, 0);
        ar  = __builtin_amdgcn_mfma_f32_16x16x32_bf16(WR[5],  XN1, ar,  0, 0, 0);
        az  = __builtin_amdgcn_mfma_f32_16x16x32_bf16(WZ[4],  XN0, az,  0, 0, 0);
        az  = __builtin_amdgcn_mfma_f32_16x16x32_bf16(WZ[5],  XN1, az,  0, 0, 0);
        anx = __builtin_amdgcn_mfma_f32_16x16x32_bf16(WNx[0], XN0, anx, 0, 0, 0);
        anx = __builtin_amdgcn_mfma_f32_16x16x32_bf16(WNx[1], XN1, anx, 0, 0, 0);
        a1  = __builtin_amdgcn_mfma_f32_16x16x32_bf16(F1[4],  XDf, a1,  0, 0, 0);

        {   // write d1 (relu) for token t-1
            int2 pk;
            pk.x = pack2bf(fmaxf(a1[0], 0.f), fmaxf(a1[1], 0.f));
            pk.y = pack2bf(fmaxf(a1[2], 0.f), fmaxf(a1[3], 0.f));
            *(int2*)&d1b[p ^ 1][col * 136 + g0] = pk;
        }

        // ---- activation + h update (registers only) ----
        const bool valid = (t < len);
#pragma unroll
        for (int r = 0; r < 4; ++r) {
            const float rg = __builtin_amdgcn_rcpf(1.f + __expf(-ar[r]));
            const float zg = __builtin_amdgcn_rcpf(1.f + __expf(-az[r]));
            const float nv = anx[r] + rg * anh[r];
            const float ng = 1.f - 2.f * __builtin_amdgcn_rcpf(1.f + __expf(2.f * nv));
            const float hnew = (1.f - zg) * ng + zg * hreg[r];
            hreg[r] = valid ? hnew : hreg[r];
        }
        {
            int2 pk;
            pk.x = pack2bf(hreg[0], hreg[1]);
            pk.y = pack2bf(hreg[2], hreg[3]);
            *(int2*)&hbf[p ^ 1][col * 136 + g0] = pk;
        }

        // ---- staging writes for next step ----
        if (t + 1 < SS)
            *(int*)&xbf[p ^ 1][srow * 72 + scol] =
                pack2bf(fmaf(xv.x, ax0, cx0), fmaf(xv.y, ax1, cx1));
        if (t < SS && tid < 256)
            *(int*)&xdbf[p ^ 1][drow * 40 + dcol] =
                pack2bf(fmaf(dv.x, ad0, cd0), fmaf(dv.y, ad1, cd1));

        sync_lds();
        p ^= 1;
    }

    {
        float4 hl;
        hl.x = hreg[0]; hl.y = hreg[1]; hl.z = hreg[2]; hl.w = hreg[3];
        *(float4*)&hlast[(size_t)(b0 + col) * HH + g0] = hl;
    }
}

// ---------------------------------------------------------------------------
extern "C" void kernel_launch(void* const* d_in, const int* in_sizes, int n_in,
                              void* d_out, int out_size, void* d_ws, size_t ws_size,
                              hipStream_t stream)
{
    (void)in_sizes; (void)n_in; (void)out_size; (void)ws_size;
    const float* x     = (const float*)d_in[0];
    const float* xd    = (const float*)d_in[1];
    const int*   lens  = (const int*)d_in[2];
    const float* bn_g  = (const float*)d_in[3];
    const float* bn_b  = (const float*)d_in[4];
    const float* bnd_g = (const float*)d_in[5];
    const float* bnd_b = (const float*)d_in[6];
    const float* Wih   = (const float*)d_in[7];
    const float* Whh   = (const float*)d_in[8];
    const float* bih   = (const float*)d_in[9];
    const float* bhh   = (const float*)d_in[10];
    // d_in[11], d_in[12]: attn_W, attn_b — softmax over size-1 axis == identity
    const float* W1    = (const float*)d_in[13];
    const float* b1    = (const float*)d_in[14];
    const float* W2    = (const float*)d_in[15];
    const float* b2    = (const float*)d_in[16];
    const float* W3    = (const float*)d_in[17];
    const float* b3    = (const float*)d_in[18];

    float* out   = (float*)d_out;
    float* hlast = out + (size_t)SS * BB * HH;

    double* acc = (double*)d_ws;                       // 192 doubles
    float*  der = (float*)((char*)d_ws + 2048);        // 192 floats

    hipMemsetAsync(d_ws, 0, 2048, stream);

    const int rows = SS * BB;
    stats_kernel<<<256, 256, 0, stream>>>(x,  lens, acc,       acc + 64,  II, rows, rows / 256);
    stats_kernel<<<256, 256, 0, stream>>>(xd, lens, acc + 128, acc + 160, DD, rows, rows / 256);
    finalize_kernel<<<1, 128, 0, stream>>>(lens, acc, bn_g, bn_b, bnd_g, bnd_b, der);

    gru_mlp_kernel<<<BB / 16, 512, 0, stream>>>(x, xd, lens, Wih, Whh, bih, bhh,
                                                W1, b1, W2, b2, W3, b3,
                                                der, out, hlast);
}

// Round 5
// 573.859 us; speedup vs baseline: 1.0680x; 1.0680x over previous
//
#include <hip/hip_runtime.h>
#include <hip/hip_bf16.h>

#define SS 256
#define BB 512
#define II 64
#define HH 128
#define DD 32

typedef __attribute__((ext_vector_type(8))) short short8;   // 8 bf16 (4 VGPRs)
typedef __attribute__((ext_vector_type(4))) float f32x4;

__device__ __forceinline__ short f2bf(float f) {
    unsigned u = __builtin_bit_cast(unsigned, f);
    u += 0x7FFFu + ((u >> 16) & 1u);            // RNE
    return (short)(u >> 16);
}
__device__ __forceinline__ int pack2bf(float a, float b) {
    return (int)((((unsigned)(unsigned short)f2bf(b)) << 16) |
                  ((unsigned)(unsigned short)f2bf(a)));
}
__device__ __forceinline__ short8 load8bf(const float* p) {
    short8 r;
#pragma unroll
    for (int j = 0; j < 8; ++j) r[j] = f2bf(p[j]);
    return r;
}

// barrier with LDS-only drain: out stores and x prefetches stay in flight
__device__ __forceinline__ void sync_lds() {
    __builtin_amdgcn_s_waitcnt(0xc07f);   // lgkmcnt(0); vmcnt/expcnt = max
    __builtin_amdgcn_s_barrier();
}

// ---------------------------------------------------------------------------
// K1: masked per-channel sum/sumsq for BOTH x (C=64) and x_d (C=32) in one
// launch. blocks [0,256) -> x, [256,384) -> x_d.
// acc layout: [0:64]=sum_x [64:128]=sq_x [128:160]=sum_d [160:192]=sq_d
// ---------------------------------------------------------------------------
__global__ __launch_bounds__(256) void stats_kernel(
    const float* __restrict__ x, const float* __restrict__ xd,
    const int* __restrict__ lengths, double* __restrict__ acc)
{
    __shared__ float red_s[256];
    __shared__ float red_q[256];
    const int rows = SS * BB;
    int blk = blockIdx.x;
    const float* v;
    int C, rpb, base;
    if (blk < 256) { v = x;  C = II; rpb = rows / 256; base = 0; }
    else           { v = xd; C = DD; rpb = rows / 128; base = 128; blk -= 256; }

    const int tid = threadIdx.x;
    const int c   = tid & (C - 1);
    const int rg  = tid / C;
    const int rpg = 256 / C;
    const int r0  = blk * rpb;
    const int r1  = r0 + rpb;
    float s = 0.f, q = 0.f;
    for (int r = r0 + rg; r < r1; r += rpg) {
        const int b  = r & (BB - 1);
        const int si = r >> 9;
        if (si < lengths[b]) {
            const float xv = v[(size_t)r * C + c];
            s += xv;
            q  = fmaf(xv, xv, q);
        }
    }
    red_s[tid] = s; red_q[tid] = q;
    __syncthreads();
    if (rg == 0) {
        for (int g = 1; g < rpg; ++g) { s += red_s[c + g * C]; q += red_q[c + g * C]; }
        atomicAdd(&acc[base + c],     (double)s);
        atomicAdd(&acc[base + C + c], (double)q);
    }
}

// ---------------------------------------------------------------------------
// K2: finalize -> folded BN coefficients  xn = x*a + c
// der layout: [0:64]=a_x [64:128]=c_x [128:160]=a_d [160:192]=c_d
// ---------------------------------------------------------------------------
__global__ __launch_bounds__(128) void finalize_kernel(
    const int* __restrict__ lengths, const double* __restrict__ acc,
    const float* __restrict__ bn_g, const float* __restrict__ bn_b,
    const float* __restrict__ bnd_g, const float* __restrict__ bnd_b,
    float* __restrict__ der)
{
    __shared__ int redc[128];
    __shared__ double s_inv;
    const int tid = threadIdx.x;
    int cs = 0;
    for (int i = tid; i < BB; i += 128) cs += lengths[i];
    redc[tid] = cs;
    __syncthreads();
    if (tid == 0) {
        int tot = 0;
        for (int i = 0; i < 128; ++i) tot += redc[i];
        s_inv = 1.0 / (double)tot;
    }
    __syncthreads();
    const double inv = s_inv;
    if (tid < 64) {
        const double mu  = acc[tid] * inv;
        const double var = acc[64 + tid] * inv - mu * mu;
        const float  rs  = rsqrtf((float)(var + 1e-5));
        const float  a   = rs * bn_g[tid];
        der[tid]      = a;
        der[64 + tid] = bn_b[tid] - (float)mu * a;
    } else if (tid < 96) {
        const int i = tid - 64;
        const double mu  = acc[128 + i] * inv;
        const double var = acc[160 + i] * inv - mu * mu;
        const float  rs  = rsqrtf((float)(var + 1e-5));
        const float  a   = rs * bnd_g[i];
        der[128 + i] = a;
        der[160 + i] = bnd_b[i] - (float)mu * a;
    }
}

// ---------------------------------------------------------------------------
// K3: fused GRU + 3-layer MLP. 32 blocks x 512 threads; block = 16 batch rows.
// Transposed MFMA form: D = W_frag (A) x act_frag (B) -> lane holds 4
// consecutive units x 1 token. Weights VGPR-resident (31 frag-sets = 124
// VGPR) -- REQUIRES the 256-VGPR budget: __launch_bounds__(512, 2). At 128
// VGPR (round 4) the compiler spills the loop body to scratch -> +1200
// cyc/step. 2 waves/SIMD x 256 VGPR = the full 512-reg file, 1 block/CU.
// MLP pipelined 3 steps behind the recurrence; all LDS double-buffered;
// ONE lgkm-only barrier per step (stores/prefetches stay in flight).
// ---------------------------------------------------------------------------
__global__ __launch_bounds__(512, 2) void gru_mlp_kernel(
    const float* __restrict__ x, const float* __restrict__ xd,
    const int* __restrict__ lengths,
    const float* __restrict__ Wih, const float* __restrict__ Whh,
    const float* __restrict__ bih, const float* __restrict__ bhh,
    const float* __restrict__ W1, const float* __restrict__ b1v,
    const float* __restrict__ W2, const float* __restrict__ b2v,
    const float* __restrict__ W3, const float* __restrict__ b3v,
    const float* __restrict__ der,
    float* __restrict__ out, float* __restrict__ hlast)
{
    __shared__ __align__(16) short hbf[2][16 * 136];
    __shared__ __align__(16) short xbf[2][16 * 72];
    __shared__ __align__(16) short xdbf[2][16 * 40];
    __shared__ __align__(16) short d1b[2][16 * 136];
    __shared__ __align__(16) short d2b[2][16 * 136];

    const int tid  = threadIdx.x;
    const int w    = tid >> 6;
    const int l    = tid & 63;
    const int col  = l & 15;       // B-frag n index = token row
    const int quad = l >> 4;
    const int b0   = blockIdx.x * 16;
    const int ur   = 16 * w + col;        // weight row for A-frags
    const int g0   = 16 * w + quad * 4;   // first output unit of this lane

    // ---- weight A-fragments (persistent in VGPRs) ----
    short8 WR[6], WZ[6], WNh[4], WNx[2], F1[5], F2[4], F3[4];
#pragma unroll
    for (int ks = 0; ks < 4; ++ks) {
        const int ko = ks * 32 + quad * 8;
        WR[ks]  = load8bf(&Whh[(size_t)ur * HH + ko]);
        WZ[ks]  = load8bf(&Whh[(size_t)(HH + ur) * HH + ko]);
        WNh[ks] = load8bf(&Whh[(size_t)(2 * HH + ur) * HH + ko]);
        F2[ks]  = load8bf(&W2[(size_t)ur * HH + ko]);
        F3[ks]  = load8bf(&W3[(size_t)ur * HH + ko]);
    }
#pragma unroll
    for (int ks = 0; ks < 2; ++ks) {
        const int ko = ks * 32 + quad * 8;
        WR[4 + ks] = load8bf(&Wih[(size_t)ur * II + ko]);
        WZ[4 + ks] = load8bf(&Wih[(size_t)(HH + ur) * II + ko]);
        WNx[ks]    = load8bf(&Wih[(size_t)(2 * HH + ur) * II + ko]);
    }
#pragma unroll
    for (int ks = 0; ks < 5; ++ks)
        F1[ks] = load8bf(&W1[(size_t)ur * 160 + ks * 32 + quad * 8]);

    float br_[4], bz_[4], bnh_[4], bnx_[4], bb1_[4], bb2_[4], bb3_[4];
#pragma unroll
    for (int r = 0; r < 4; ++r) {
        const int g = g0 + r;
        br_[r]  = bih[g] + bhh[g];
        bz_[r]  = bih[HH + g] + bhh[HH + g];
        bnh_[r] = bhh[2 * HH + g];
        bnx_[r] = bih[2 * HH + g];
        bb1_[r] = b1v[g]; bb2_[r] = b2v[g]; bb3_[r] = b3v[g];
    }
    const int len = lengths[b0 + col];

    // staging maps
    const int srow = tid >> 5, scol = (tid & 31) * 2;
    const float ax0 = der[scol],      ax1 = der[scol + 1];
    const float cx0 = der[64 + scol], cx1 = der[64 + scol + 1];
    const int drow = tid >> 4, dcol = (tid & 15) * 2;   // tid<256 only
    float ad0 = 0.f, ad1 = 0.f, cd0 = 0.f, cd1 = 0.f;
    if (tid < 256) {
        ad0 = der[128 + dcol]; ad1 = der[128 + dcol + 1];
        cd0 = der[160 + dcol]; cd1 = der[160 + dcol + 1];
    }

    // init: zero h, stage xn[0]
    for (int i = tid; i < 16 * 136 / 2; i += 512) ((int*)hbf[0])[i] = 0;
    float hreg[4] = {0.f, 0.f, 0.f, 0.f};
    {
        const float2 xv = *(const float2*)&x[(size_t)(b0 + srow) * II + scol];
        *(int*)&xbf[0][srow * 72 + scol] =
            pack2bf(fmaf(xv.x, ax0, cx0), fmaf(xv.y, ax1, cx1));
    }
    sync_lds();

    int p = 0;
    for (int t = 0; t < SS + 3; ++t) {
        // global prefetches (drain-free across the barrier)
        float2 xv, dv;
        if (t + 1 < SS)
            xv = *(const float2*)&x[(size_t)((t + 1) * BB + b0 + srow) * II + scol];
        if (t < SS && tid < 256)
            dv = *(const float2*)&xd[(size_t)(t * BB + b0 + drow) * DD + dcol];

        // ---- phase A: L3 for token t-3 ----
        f32x4 a3 = {bb3_[0], bb3_[1], bb3_[2], bb3_[3]};
#pragma unroll
        for (int ks = 0; ks < 4; ++ks)
            a3 = __builtin_amdgcn_mfma_f32_16x16x32_bf16(
                F3[ks], *(const short8*)&d2b[p][col * 136 + ks * 32 + quad * 8], a3, 0, 0, 0);
        if (t >= 3) {
            const int tau = t - 3;
            const bool v = tau < len;
            float4 o;
            o.x = v ? fmaxf(a3[0], 0.f) : 0.f;
            o.y = v ? fmaxf(a3[1], 0.f) : 0.f;
            o.z = v ? fmaxf(a3[2], 0.f) : 0.f;
            o.w = v ? fmaxf(a3[3], 0.f) : 0.f;
            *(float4*)&out[((size_t)tau * BB + b0 + col) * HH + g0] = o;
        }

        // ---- phase B: L2 for token t-2 ----
        f32x4 a2 = {bb2_[0], bb2_[1], bb2_[2], bb2_[3]};
#pragma unroll
        for (int ks = 0; ks < 4; ++ks)
            a2 = __builtin_amdgcn_mfma_f32_16x16x32_bf16(
                F2[ks], *(const short8*)&d1b[p][col * 136 + ks * 32 + quad * 8], a2, 0, 0, 0);
        {
            int2 pk;
            pk.x = pack2bf(fmaxf(a2[0], 0.f), fmaxf(a2[1], 0.f));
            pk.y = pack2bf(fmaxf(a2[2], 0.f), fmaxf(a2[3], 0.f));
            *(int2*)&d2b[p ^ 1][col * 136 + g0] = pk;
        }

        // ---- phase C: gates (step t) + L1 (token t-1), shared h A-frags ----
        short8 Hf[4];
#pragma unroll
        for (int ks = 0; ks < 4; ++ks)
            Hf[ks] = *(const short8*)&hbf[p][col * 136 + ks * 32 + quad * 8];
        const short8 XN0 = *(const short8*)&xbf[p][col * 72 + quad * 8];
        const short8 XN1 = *(const short8*)&xbf[p][col * 72 + 32 + quad * 8];
        const short8 XDf = *(const short8*)&xdbf[p][col * 40 + quad * 8];

        f32x4 ar  = {br_[0],  br_[1],  br_[2],  br_[3]};
        f32x4 az  = {bz_[0],  bz_[1],  bz_[2],  bz_[3]};
        f32x4 anh = {bnh_[0], bnh_[1], bnh_[2], bnh_[3]};
        f32x4 anx = {bnx_[0], bnx_[1], bnx_[2], bnx_[3]};
        f32x4 a1  = {bb1_[0], bb1_[1], bb1_[2], bb1_[3]};
#pragma unroll
        for (int ks = 0; ks < 4; ++ks) {
            ar  = __builtin_amdgcn_mfma_f32_16x16x32_bf16(WR[ks],  Hf[ks], ar,  0, 0, 0);
            az  = __builtin_amdgcn_mfma_f32_16x16x32_bf16(WZ[ks],  Hf[ks], az,  0, 0, 0);
            anh = __builtin_amdgcn_mfma_f32_16x16x32_bf16(WNh[ks], Hf[ks], anh, 0, 0, 0);
            a1  = __builtin_amdgcn_mfma_f32_16x16x32_bf16(F1[ks],  Hf[ks], a1,  0, 0, 0);
        }
        ar  = __builtin_amdgcn_mfma_f32_16x16x32_bf16(WR[4],  XN0, ar,  0, 0, 0);
        ar  = __builtin_amdgcn_mfma_f32_16x16x32_bf16(WR[5],  XN1, ar,  0, 0, 0);
        az  = __builtin_amdgcn_mfma_f32_16x16x32_bf16(WZ[4],  XN0, az,  0, 0, 0);
        az  = __builtin_amdgcn_mfma_f32_16x16x32_bf16(WZ[5],  XN1, az,  0, 0, 0);
        anx = __builtin_amdgcn_mfma_f32_16x16x32_bf16(WNx[0], XN0, anx, 0, 0, 0);
        anx = __builtin_amdgcn_mfma_f32_16x16x32_bf16(WNx[1], XN1, anx, 0, 0, 0);
        a1  = __builtin_amdgcn_mfma_f32_16x16x32_bf16(F1[4],  XDf, a1,  0, 0, 0);

        {   // write d1 (relu) for token t-1
            int2 pk;
            pk.x = pack2bf(fmaxf(a1[0], 0.f), fmaxf(a1[1], 0.f));
            pk.y = pack2bf(fmaxf(a1[2], 0.f), fmaxf(a1[3], 0.f));
            *(int2*)&d1b[p ^ 1][col * 136 + g0] = pk;
        }

        // ---- activation + h update (registers only) ----
        const bool valid = (t < len);
#pragma unroll
        for (int r = 0; r < 4; ++r) {
            const float rg = __builtin_amdgcn_rcpf(1.f + __expf(-ar[r]));
            const float zg = __builtin_amdgcn_rcpf(1.f + __expf(-az[r]));
            const float nv = anx[r] + rg * anh[r];
            const float ng = 1.f - 2.f * __builtin_amdgcn_rcpf(1.f + __expf(2.f * nv));
            const float hnew = (1.f - zg) * ng + zg * hreg[r];
            hreg[r] = valid ? hnew : hreg[r];
        }
        {
            int2 pk;
            pk.x = pack2bf(hreg[0], hreg[1]);
            pk.y = pack2bf(hreg[2], hreg[3]);
            *(int2*)&hbf[p ^ 1][col * 136 + g0] = pk;
        }

        // ---- staging writes for next step ----
        if (t + 1 < SS)
            *(int*)&xbf[p ^ 1][srow * 72 + scol] =
                pack2bf(fmaf(xv.x, ax0, cx0), fmaf(xv.y, ax1, cx1));
        if (t < SS && tid < 256)
            *(int*)&xdbf[p ^ 1][drow * 40 + dcol] =
                pack2bf(fmaf(dv.x, ad0, cd0), fmaf(dv.y, ad1, cd1));

        sync_lds();
        p ^= 1;
    }

    {
        float4 hl;
        hl.x = hreg[0]; hl.y = hreg[1]; hl.z = hreg[2]; hl.w = hreg[3];
        *(float4*)&hlast[(size_t)(b0 + col) * HH + g0] = hl;
    }
}

// ---------------------------------------------------------------------------
extern "C" void kernel_launch(void* const* d_in, const int* in_sizes, int n_in,
                              void* d_out, int out_size, void* d_ws, size_t ws_size,
                              hipStream_t stream)
{
    (void)in_sizes; (void)n_in; (void)out_size; (void)ws_size;
    const float* x     = (const float*)d_in[0];
    const float* xd    = (const float*)d_in[1];
    const int*   lens  = (const int*)d_in[2];
    const float* bn_g  = (const float*)d_in[3];
    const float* bn_b  = (const float*)d_in[4];
    const float* bnd_g = (const float*)d_in[5];
    const float* bnd_b = (const float*)d_in[6];
    const float* Wih   = (const float*)d_in[7];
    const float* Whh   = (const float*)d_in[8];
    const float* bih   = (const float*)d_in[9];
    const float* bhh   = (const float*)d_in[10];
    // d_in[11], d_in[12]: attn_W, attn_b — softmax over size-1 axis == identity
    const float* W1    = (const float*)d_in[13];
    const float* b1    = (const float*)d_in[14];
    const float* W2    = (const float*)d_in[15];
    const float* b2    = (const float*)d_in[16];
    const float* W3    = (const float*)d_in[17];
    const float* b3    = (const float*)d_in[18];

    float* out   = (float*)d_out;
    float* hlast = out + (size_t)SS * BB * HH;

    double* acc = (double*)d_ws;                       // 192 doubles
    float*  der = (float*)((char*)d_ws + 2048);        // 192 floats

    hipMemsetAsync(d_ws, 0, 2048, stream);

    stats_kernel<<<384, 256, 0, stream>>>(x, xd, lens, acc);
    finalize_kernel<<<1, 128, 0, stream>>>(lens, acc, bn_g, bn_b, bnd_g, bnd_b, der);

    gru_mlp_kernel<<<BB / 16, 512, 0, stream>>>(x, xd, lens, Wih, Whh, bih, bhh,
                                                W1, b1, W2, b2, W3, b3,
                                                der, out, hlast);
}

// Round 6
// 470.011 us; speedup vs baseline: 1.3040x; 1.2209x over previous
//
#include <hip/hip_runtime.h>
#include <hip/hip_bf16.h>

#define SS 256
#define BB 512
#define II 64
#define HH 128
#define DD 32

typedef __attribute__((ext_vector_type(8))) short short8;   // 8 bf16 (4 VGPRs)
typedef __attribute__((ext_vector_type(4))) float f32x4;

__device__ __forceinline__ short f2bf(float f) {
    unsigned u = __builtin_bit_cast(unsigned, f);
    u += 0x7FFFu + ((u >> 16) & 1u);            // RNE
    return (short)(u >> 16);
}
__device__ __forceinline__ int pack2bf(float a, float b) {
    return (int)((((unsigned)(unsigned short)f2bf(b)) << 16) |
                  ((unsigned)(unsigned short)f2bf(a)));
}
__device__ __forceinline__ short8 load8bf(const float* p) {
    short8 r;
#pragma unroll
    for (int j = 0; j < 8; ++j) r[j] = f2bf(p[j]);
    return r;
}

// barrier with LDS-only drain: global stores/prefetches stay in flight
__device__ __forceinline__ void sync_lds() {
    __builtin_amdgcn_s_waitcnt(0xc07f);   // lgkmcnt(0); vmcnt/expcnt = max
    __builtin_amdgcn_s_barrier();
}

// ---------------------------------------------------------------------------
// K1: masked per-channel sum/sumsq for BOTH x (C=64) and x_d (C=32) in one
// launch. blocks [0,256) -> x, [256,384) -> x_d.
// acc layout: [0:64]=sum_x [64:128]=sq_x [128:160]=sum_d [160:192]=sq_d
// ---------------------------------------------------------------------------
__global__ __launch_bounds__(256) void stats_kernel(
    const float* __restrict__ x, const float* __restrict__ xd,
    const int* __restrict__ lengths, double* __restrict__ acc)
{
    __shared__ float red_s[256];
    __shared__ float red_q[256];
    const int rows = SS * BB;
    int blk = blockIdx.x;
    const float* v;
    int C, rpb, base;
    if (blk < 256) { v = x;  C = II; rpb = rows / 256; base = 0; }
    else           { v = xd; C = DD; rpb = rows / 128; base = 128; blk -= 256; }

    const int tid = threadIdx.x;
    const int c   = tid & (C - 1);
    const int rg  = tid / C;
    const int rpg = 256 / C;
    const int r0  = blk * rpb;
    const int r1  = r0 + rpb;
    float s = 0.f, q = 0.f;
    for (int r = r0 + rg; r < r1; r += rpg) {
        const int b  = r & (BB - 1);
        const int si = r >> 9;
        if (si < lengths[b]) {
            const float xv = v[(size_t)r * C + c];
            s += xv;
            q  = fmaf(xv, xv, q);
        }
    }
    red_s[tid] = s; red_q[tid] = q;
    __syncthreads();
    if (rg == 0) {
        for (int g = 1; g < rpg; ++g) { s += red_s[c + g * C]; q += red_q[c + g * C]; }
        atomicAdd(&acc[base + c],     (double)s);
        atomicAdd(&acc[base + C + c], (double)q);
    }
}

// ---------------------------------------------------------------------------
// K2: finalize -> folded BN coefficients  xn = x*a + c
// der layout: [0:64]=a_x [64:128]=c_x [128:160]=a_d [160:192]=c_d
// ---------------------------------------------------------------------------
__global__ __launch_bounds__(128) void finalize_kernel(
    const int* __restrict__ lengths, const double* __restrict__ acc,
    const float* __restrict__ bn_g, const float* __restrict__ bn_b,
    const float* __restrict__ bnd_g, const float* __restrict__ bnd_b,
    float* __restrict__ der)
{
    __shared__ int redc[128];
    __shared__ double s_inv;
    const int tid = threadIdx.x;
    int cs = 0;
    for (int i = tid; i < BB; i += 128) cs += lengths[i];
    redc[tid] = cs;
    __syncthreads();
    if (tid == 0) {
        int tot = 0;
        for (int i = 0; i < 128; ++i) tot += redc[i];
        s_inv = 1.0 / (double)tot;
    }
    __syncthreads();
    const double inv = s_inv;
    if (tid < 64) {
        const double mu  = acc[tid] * inv;
        const double var = acc[64 + tid] * inv - mu * mu;
        const float  rs  = rsqrtf((float)(var + 1e-5));
        const float  a   = rs * bn_g[tid];
        der[tid]      = a;
        der[64 + tid] = bn_b[tid] - (float)mu * a;
    } else if (tid < 96) {
        const int i = tid - 64;
        const double mu  = acc[128 + i] * inv;
        const double var = acc[160 + i] * inv - mu * mu;
        const float  rs  = rsqrtf((float)(var + 1e-5));
        const float  a   = rs * bnd_g[i];
        der[128 + i] = a;
        der[160 + i] = bnd_b[i] - (float)mu * a;
    }
}

// ---------------------------------------------------------------------------
// K3: GRU only. 32 blocks x 512 threads; block = 16 batch rows.
// Transposed MFMA: D = W_frag (A) x act_frag (B); lane owns 4 consecutive
// units x 1 token -> float4 ys stores, int2 h writes. Weights VGPR-resident
// (18 frags = 72 VGPR). ONE lgkm-only barrier per step; ys stores and x
// prefetches never drained inside the loop. ys carries hreg even for invalid
// tokens (the MLP's final mask makes those values irrelevant).
// ---------------------------------------------------------------------------
__global__ __launch_bounds__(512, 2) void gru_kernel(
    const float* __restrict__ x, const int* __restrict__ lengths,
    const float* __restrict__ Wih, const float* __restrict__ Whh,
    const float* __restrict__ bih, const float* __restrict__ bhh,
    const float* __restrict__ der,
    float* __restrict__ ys, float* __restrict__ hlast)
{
    __shared__ __align__(16) short hbf[2][16 * 136];
    __shared__ __align__(16) short xbf[2][16 * 72];

    const int tid  = threadIdx.x;
    const int w    = tid >> 6;
    const int l    = tid & 63;
    const int col  = l & 15;       // token (batch row within block)
    const int quad = l >> 4;
    const int b0   = blockIdx.x * 16;
    const int ur   = 16 * w + col;        // weight row for A-frags
    const int g0   = 16 * w + quad * 4;   // first output unit of this lane

    short8 WR[6], WZ[6], WNh[4], WNx[2];
#pragma unroll
    for (int ks = 0; ks < 4; ++ks) {
        const int ko = ks * 32 + quad * 8;
        WR[ks]  = load8bf(&Whh[(size_t)ur * HH + ko]);
        WZ[ks]  = load8bf(&Whh[(size_t)(HH + ur) * HH + ko]);
        WNh[ks] = load8bf(&Whh[(size_t)(2 * HH + ur) * HH + ko]);
    }
#pragma unroll
    for (int ks = 0; ks < 2; ++ks) {
        const int ko = ks * 32 + quad * 8;
        WR[4 + ks] = load8bf(&Wih[(size_t)ur * II + ko]);
        WZ[4 + ks] = load8bf(&Wih[(size_t)(HH + ur) * II + ko]);
        WNx[ks]    = load8bf(&Wih[(size_t)(2 * HH + ur) * II + ko]);
    }
    float br_[4], bz_[4], bnh_[4], bnx_[4];
#pragma unroll
    for (int r = 0; r < 4; ++r) {
        const int g = g0 + r;
        br_[r]  = bih[g] + bhh[g];
        bz_[r]  = bih[HH + g] + bhh[HH + g];
        bnh_[r] = bhh[2 * HH + g];
        bnx_[r] = bih[2 * HH + g];
    }
    const int len = lengths[b0 + col];

    // x staging: all 512 threads, one float2 each (16 rows x 64 cols)
    const int srow = tid >> 5, scol = (tid & 31) * 2;
    const float ax0 = der[scol],      ax1 = der[scol + 1];
    const float cx0 = der[64 + scol], cx1 = der[64 + scol + 1];

    for (int i = tid; i < 16 * 136 / 2; i += 512) ((int*)hbf[0])[i] = 0;
    float hreg[4] = {0.f, 0.f, 0.f, 0.f};
    {
        const float2 xv = *(const float2*)&x[(size_t)(b0 + srow) * II + scol];
        *(int*)&xbf[0][srow * 72 + scol] =
            pack2bf(fmaf(xv.x, ax0, cx0), fmaf(xv.y, ax1, cx1));
    }
    sync_lds();

    int p = 0;
    for (int t = 0; t < SS; ++t) {
        float2 xv;
        if (t + 1 < SS)
            xv = *(const float2*)&x[(size_t)((t + 1) * BB + b0 + srow) * II + scol];

        short8 Hf[4];
#pragma unroll
        for (int ks = 0; ks < 4; ++ks)
            Hf[ks] = *(const short8*)&hbf[p][col * 136 + ks * 32 + quad * 8];
        const short8 XN0 = *(const short8*)&xbf[p][col * 72 + quad * 8];
        const short8 XN1 = *(const short8*)&xbf[p][col * 72 + 32 + quad * 8];

        f32x4 ar  = {br_[0],  br_[1],  br_[2],  br_[3]};
        f32x4 az  = {bz_[0],  bz_[1],  bz_[2],  bz_[3]};
        f32x4 anh = {bnh_[0], bnh_[1], bnh_[2], bnh_[3]};
        f32x4 anx = {bnx_[0], bnx_[1], bnx_[2], bnx_[3]};
#pragma unroll
        for (int ks = 0; ks < 4; ++ks) {
            ar  = __builtin_amdgcn_mfma_f32_16x16x32_bf16(WR[ks],  Hf[ks], ar,  0, 0, 0);
            az  = __builtin_amdgcn_mfma_f32_16x16x32_bf16(WZ[ks],  Hf[ks], az,  0, 0, 0);
            anh = __builtin_amdgcn_mfma_f32_16x16x32_bf16(WNh[ks], Hf[ks], anh, 0, 0, 0);
        }
        ar  = __builtin_amdgcn_mfma_f32_16x16x32_bf16(WR[4],  XN0, ar,  0, 0, 0);
        ar  = __builtin_amdgcn_mfma_f32_16x16x32_bf16(WR[5],  XN1, ar,  0, 0, 0);
        az  = __builtin_amdgcn_mfma_f32_16x16x32_bf16(WZ[4],  XN0, az,  0, 0, 0);
        az  = __builtin_amdgcn_mfma_f32_16x16x32_bf16(WZ[5],  XN1, az,  0, 0, 0);
        anx = __builtin_amdgcn_mfma_f32_16x16x32_bf16(WNx[0], XN0, anx, 0, 0, 0);
        anx = __builtin_amdgcn_mfma_f32_16x16x32_bf16(WNx[1], XN1, anx, 0, 0, 0);

        const bool valid = (t < len);
#pragma unroll
        for (int r = 0; r < 4; ++r) {
            const float rg = __builtin_amdgcn_rcpf(1.f + __expf(-ar[r]));
            const float zg = __builtin_amdgcn_rcpf(1.f + __expf(-az[r]));
            const float nv = anx[r] + rg * anh[r];
            const float ng = 1.f - 2.f * __builtin_amdgcn_rcpf(1.f + __expf(2.f * nv));
            const float hnew = (1.f - zg) * ng + zg * hreg[r];
            hreg[r] = valid ? hnew : hreg[r];
        }
        {   // ys store (drain-free) + bf16 h for next step
            float4 o;
            o.x = hreg[0]; o.y = hreg[1]; o.z = hreg[2]; o.w = hreg[3];
            *(float4*)&ys[((size_t)t * BB + b0 + col) * HH + g0] = o;
            int2 pk;
            pk.x = pack2bf(hreg[0], hreg[1]);
            pk.y = pack2bf(hreg[2], hreg[3]);
            *(int2*)&hbf[p ^ 1][col * 136 + g0] = pk;
        }
        if (t + 1 < SS)
            *(int*)&xbf[p ^ 1][srow * 72 + scol] =
                pack2bf(fmaf(xv.x, ax0, cx0), fmaf(xv.y, ax1, cx1));

        sync_lds();
        p ^= 1;
    }

    {
        float4 hl;
        hl.x = hreg[0]; hl.y = hreg[1]; hl.z = hreg[2]; hl.w = hreg[3];
        *(float4*)&hlast[(size_t)(b0 + col) * HH + g0] = hl;
    }
}

// ---------------------------------------------------------------------------
// K4: 3-layer MLP, in-place on d_out. 512 blocks x 512 threads; 16 tiles of
// 16 tokens per block, 3-stage pipeline (L1 tile i / L2 i-1 / L3 i-2) with
// ONE lgkm-only barrier per step; next tile's y/xd prefetched in registers.
// Weights VGPR-resident (13 frags = 52 VGPR).
// ---------------------------------------------------------------------------
__global__ __launch_bounds__(512, 2) void mlp_kernel(
    const float* __restrict__ xd, const int* __restrict__ lengths,
    const float* __restrict__ W1, const float* __restrict__ b1v,
    const float* __restrict__ W2, const float* __restrict__ b2v,
    const float* __restrict__ W3, const float* __restrict__ b3v,
    const float* __restrict__ der, float* io)
{
    __shared__ __align__(16) short z0[2][16 * 168];
    __shared__ __align__(16) short d1b[2][16 * 136];
    __shared__ __align__(16) short d2b[2][16 * 136];

    const int tid  = threadIdx.x;
    const int w    = tid >> 6;
    const int l    = tid & 63;
    const int col  = l & 15;
    const int quad = l >> 4;
    const int ur   = 16 * w + col;
    const int g0   = 16 * w + quad * 4;

    short8 F1[5], F2[4], F3[4];
#pragma unroll
    for (int ks = 0; ks < 5; ++ks)
        F1[ks] = load8bf(&W1[(size_t)ur * 160 + ks * 32 + quad * 8]);
#pragma unroll
    for (int ks = 0; ks < 4; ++ks) {
        const int ko = ks * 32 + quad * 8;
        F2[ks] = load8bf(&W2[(size_t)ur * HH + ko]);
        F3[ks] = load8bf(&W3[(size_t)ur * HH + ko]);
    }
    float bb1_[4], bb2_[4], bb3_[4];
#pragma unroll
    for (int r = 0; r < 4; ++r) {
        bb1_[r] = b1v[g0 + r]; bb2_[r] = b2v[g0 + r]; bb3_[r] = b3v[g0 + r];
    }

    // staging maps: y = 512 thr x float4 (16x128); xd = 256 thr x float2 (16x32)
    const int yrow = tid >> 5, yc = (tid & 31) * 4;
    const int drow = tid >> 4, dcol = (tid & 15) * 2;
    float ad0 = 0.f, ad1 = 0.f, cd0 = 0.f, cd1 = 0.f;
    if (tid < 256) {
        ad0 = der[128 + dcol]; ad1 = der[128 + dcol + 1];
        cd0 = der[160 + dcol]; cd1 = der[160 + dcol + 1];
    }

    const int tile0 = blockIdx.x * 16;

    {   // pre-stage tile 0
        const size_t tok0 = (size_t)tile0 * 16;
        const float4 yv = *(const float4*)&io[(tok0 + yrow) * HH + yc];
        int2 pk;
        pk.x = pack2bf(yv.x, yv.y);
        pk.y = pack2bf(yv.z, yv.w);
        *(int2*)&z0[0][yrow * 168 + yc] = pk;
        if (tid < 256) {
            const float2 dv = *(const float2*)&xd[(tok0 + drow) * DD + dcol];
            *(int*)&z0[0][drow * 168 + HH + dcol] =
                pack2bf(fmaf(dv.x, ad0, cd0), fmaf(dv.y, ad1, cd1));
        }
    }
    sync_lds();

    int p = 0;
    for (int it = 0; it <= 17; ++it) {
        // prefetch tile it+1 into registers
        float4 yv; float2 dv;
        const int nt = it + 1;
        if (nt <= 15) {
            const size_t tok0n = (size_t)(tile0 + nt) * 16;
            yv = *(const float4*)&io[(tok0n + yrow) * HH + yc];
            if (tid < 256) dv = *(const float2*)&xd[(tok0n + drow) * DD + dcol];
        }

        // L1 (tile it): z0[p] -> d1b[p^1]
        f32x4 a1 = {bb1_[0], bb1_[1], bb1_[2], bb1_[3]};
#pragma unroll
        for (int ks = 0; ks < 5; ++ks)
            a1 = __builtin_amdgcn_mfma_f32_16x16x32_bf16(
                F1[ks], *(const short8*)&z0[p][col * 168 + ks * 32 + quad * 8], a1, 0, 0, 0);
        {
            int2 pk;
            pk.x = pack2bf(fmaxf(a1[0], 0.f), fmaxf(a1[1], 0.f));
            pk.y = pack2bf(fmaxf(a1[2], 0.f), fmaxf(a1[3], 0.f));
            *(int2*)&d1b[p ^ 1][col * 136 + g0] = pk;
        }

        // L2 (tile it-1): d1b[p] -> d2b[p^1]
        f32x4 a2 = {bb2_[0], bb2_[1], bb2_[2], bb2_[3]};
#pragma unroll
        for (int ks = 0; ks < 4; ++ks)
            a2 = __builtin_amdgcn_mfma_f32_16x16x32_bf16(
                F2[ks], *(const short8*)&d1b[p][col * 136 + ks * 32 + quad * 8], a2, 0, 0, 0);
        {
            int2 pk;
            pk.x = pack2bf(fmaxf(a2[0], 0.f), fmaxf(a2[1], 0.f));
            pk.y = pack2bf(fmaxf(a2[2], 0.f), fmaxf(a2[3], 0.f));
            *(int2*)&d2b[p ^ 1][col * 136 + g0] = pk;
        }

        // L3 (tile it-2): d2b[p] -> out (drain-free store)
        f32x4 a3 = {bb3_[0], bb3_[1], bb3_[2], bb3_[3]};
#pragma unroll
        for (int ks = 0; ks < 4; ++ks)
            a3 = __builtin_amdgcn_mfma_f32_16x16x32_bf16(
                F3[ks], *(const short8*)&d2b[p][col * 136 + ks * 32 + quad * 8], a3, 0, 0, 0);
        if (it >= 2) {
            const int tok0 = (tile0 + it - 2) * 16;
            const int tI = tok0 >> 9;
            const int bI = tok0 & (BB - 1);
            const bool v = tI < lengths[bI + col];
            float4 o;
            o.x = v ? fmaxf(a3[0], 0.f) : 0.f;
            o.y = v ? fmaxf(a3[1], 0.f) : 0.f;
            o.z = v ? fmaxf(a3[2], 0.f) : 0.f;
            o.w = v ? fmaxf(a3[3], 0.f) : 0.f;
            *(float4*)&io[((size_t)tok0 + col) * HH + g0] = o;
        }

        // commit prefetched tile it+1 to z0[p^1]
        if (nt <= 15) {
            int2 pk;
            pk.x = pack2bf(yv.x, yv.y);
            pk.y = pack2bf(yv.z, yv.w);
            *(int2*)&z0[p ^ 1][yrow * 168 + yc] = pk;
            if (tid < 256)
                *(int*)&z0[p ^ 1][drow * 168 + HH + dcol] =
                    pack2bf(fmaf(dv.x, ad0, cd0), fmaf(dv.y, ad1, cd1));
        }
        sync_lds();
        p ^= 1;
    }
}

// ---------------------------------------------------------------------------
extern "C" void kernel_launch(void* const* d_in, const int* in_sizes, int n_in,
                              void* d_out, int out_size, void* d_ws, size_t ws_size,
                              hipStream_t stream)
{
    (void)in_sizes; (void)n_in; (void)out_size; (void)ws_size;
    const float* x     = (const float*)d_in[0];
    const float* xd    = (const float*)d_in[1];
    const int*   lens  = (const int*)d_in[2];
    const float* bn_g  = (const float*)d_in[3];
    const float* bn_b  = (const float*)d_in[4];
    const float* bnd_g = (const float*)d_in[5];
    const float* bnd_b = (const float*)d_in[6];
    const float* Wih   = (const float*)d_in[7];
    const float* Whh   = (const float*)d_in[8];
    const float* bih   = (const float*)d_in[9];
    const float* bhh   = (const float*)d_in[10];
    // d_in[11], d_in[12]: attn_W, attn_b — softmax over size-1 axis == identity
    const float* W1    = (const float*)d_in[13];
    const float* b1    = (const float*)d_in[14];
    const float* W2    = (const float*)d_in[15];
    const float* b2    = (const float*)d_in[16];
    const float* W3    = (const float*)d_in[17];
    const float* b3    = (const float*)d_in[18];

    float* out   = (float*)d_out;
    float* hlast = out + (size_t)SS * BB * HH;

    double* acc = (double*)d_ws;                       // 192 doubles
    float*  der = (float*)((char*)d_ws + 2048);        // 192 floats

    hipMemsetAsync(d_ws, 0, 2048, stream);

    stats_kernel<<<384, 256, 0, stream>>>(x, xd, lens, acc);
    finalize_kernel<<<1, 128, 0, stream>>>(lens, acc, bn_g, bn_b, bnd_g, bnd_b, der);

    gru_kernel<<<BB / 16, 512, 0, stream>>>(x, lens, Wih, Whh, bih, bhh, der,
                                            out, hlast);

    mlp_kernel<<<512, 512, 0, stream>>>(xd, lens, W1, b1, W2, b2, W3, b3,
                                        der, out);
}